// Round 2
// baseline (3098.382 us; speedup 1.0000x reference)
//
#include <hip/hip_runtime.h>
#include <math.h>

// DeepHeadClassifier fused kernel — round 1: dtype-dispatched correct baseline.
// NaN in round 1 pointed at input dtype mismatch (fp32 read as bf16 -> inf-inf).
// ln1_g is all-ones: first u32 word is 0x3F803F80 (bf16) vs 0x3F800000 (fp32).
// A detector kernel writes the flag to d_ws; both template instantiations
// launch and the wrong one early-exits (grid-uniform branch, graph-safe).

#define E 256
#define DD 64
#define NC 7
#define RPB 4
#define NT 256
#define QP 776   // padded stride for [768] vectors
#define RP 776

typedef unsigned short u16;
typedef unsigned int u32;

__device__ __forceinline__ float bf2f(u32 u) { return __uint_as_float(u << 16); }
__device__ __forceinline__ u16 f2bf(float f) {
    u32 u = __float_as_uint(f);
    u32 r = (u + 0x7fffu + ((u >> 16) & 1u)) >> 16;
    return (u16)r;
}

// ---- dtype-parametric load/store helpers (idx in elements) ----
template<bool BF16>
__device__ __forceinline__ void ld8(const void* base, size_t idx, float* o) {
    if constexpr (BF16) {
        const u16* p = (const u16*)base + idx;
        uint4 q = *reinterpret_cast<const uint4*>(p);
        o[0]=bf2f(q.x & 0xffffu); o[1]=bf2f(q.x >> 16);
        o[2]=bf2f(q.y & 0xffffu); o[3]=bf2f(q.y >> 16);
        o[4]=bf2f(q.z & 0xffffu); o[5]=bf2f(q.z >> 16);
        o[6]=bf2f(q.w & 0xffffu); o[7]=bf2f(q.w >> 16);
    } else {
        const float* p = (const float*)base + idx;
        float4 a = *(const float4*)p;
        float4 b = *(const float4*)(p + 4);
        o[0]=a.x; o[1]=a.y; o[2]=a.z; o[3]=a.w;
        o[4]=b.x; o[5]=b.y; o[6]=b.z; o[7]=b.w;
    }
}
template<bool BF16>
__device__ __forceinline__ void ld4(const void* base, size_t idx, float* o) {
    if constexpr (BF16) {
        const u16* p = (const u16*)base + idx;
        uint2 q = *reinterpret_cast<const uint2*>(p);
        o[0]=bf2f(q.x & 0xffffu); o[1]=bf2f(q.x >> 16);
        o[2]=bf2f(q.y & 0xffffu); o[3]=bf2f(q.y >> 16);
    } else {
        const float* p = (const float*)base + idx;
        float4 a = *(const float4*)p;
        o[0]=a.x; o[1]=a.y; o[2]=a.z; o[3]=a.w;
    }
}
template<bool BF16>
__device__ __forceinline__ float ld1(const void* base, size_t idx) {
    if constexpr (BF16) return bf2f((u32)((const u16*)base)[idx]);
    else return ((const float*)base)[idx];
}
template<bool BF16>
__device__ __forceinline__ void st1(void* base, size_t idx, float v) {
    if constexpr (BF16) ((u16*)base)[idx] = f2bf(v);
    else ((float*)base)[idx] = v;
}

__global__ void dtype_detect_kernel(const u32* ln1g_words, int* flag) {
    if (blockIdx.x == 0 && threadIdx.x == 0)
        *flag = (ln1g_words[0] == 0x3F803F80u) ? 1 : 0;
}

template<bool BF16>
__global__ __launch_bounds__(NT, 3)
void dhc_fused_kernel(
    const void* __restrict__ f0, const void* __restrict__ f1, const void* __restrict__ f2,
    const void* __restrict__ ipw, const void* __restrict__ ipb,
    const void* __restrict__ ow,  const void* __restrict__ ob,
    const void* __restrict__ ln1g, const void* __restrict__ ln1b,
    const void* __restrict__ gw,  const void* __restrict__ gb,
    const void* __restrict__ ln2g, const void* __restrict__ ln2b,
    const void* __restrict__ w1,  const void* __restrict__ bb1,
    const void* __restrict__ w2,  const void* __restrict__ bb2,
    const void* __restrict__ w3,  const void* __restrict__ bb3,
    void* __restrict__ d_out, const int* __restrict__ flag,
    int nrows)
{
    if (*flag != (BF16 ? 1 : 0)) return;   // grid-uniform dtype gate

    __shared__ float s_rows[RPB][RP];      // stacked [r][s*256+c]
    __shared__ float s_qkv[RPB][3][QP];    // [r][s][0:256)=q->ctx, [256:512)=k->x, [512:768)=v->fused/h1/h2
    __shared__ float s_mu[12], s_rstd[12];
    __shared__ float s_wgt[RPB][3];
    __shared__ float s_mu2[RPB], s_rstd2[RPB];

    const int tid = threadIdx.x;
    const long long row0 = (long long)blockIdx.x * RPB;
    const size_t fused_base = (size_t)nrows * NC;   // flat offset of fused in d_out

    // ---- P0: load stacked rows -> fp32 LDS ----
    for (int v = tid; v < RPB * 192; v += NT) {
        int flat = v * 4;
        int r = flat / 768;
        int j = flat - r * 768;
        int s = j >> 8;
        int c = j & 255;
        float tmp[4] = {0.f, 0.f, 0.f, 0.f};
        if (row0 + r < nrows) {
            const void* src = (s == 0 ? f0 : (s == 1 ? f1 : f2));
            ld4<BF16>(src, (size_t)(row0 + r) * E + c, tmp);
        }
        s_rows[r][j] = tmp[0]; s_rows[r][j+1] = tmp[1];
        s_rows[r][j+2] = tmp[2]; s_rows[r][j+3] = tmp[3];
    }
    __syncthreads();

    // ---- P1: qkv = stacked @ in_proj_w.T + b ----
    {
        float acc[3][12];
        size_t wbase[3];
        #pragma unroll
        for (int jo = 0; jo < 3; ++jo) {
            int j = tid + jo * 256;
            float bias = ld1<BF16>(ipb, j);
            wbase[jo] = (size_t)j * E;
            #pragma unroll
            for (int rs = 0; rs < 12; ++rs) acc[jo][rs] = bias;
        }
        for (int k = 0; k < E; k += 8) {
            float w[3][8];
            #pragma unroll
            for (int jo = 0; jo < 3; ++jo) ld8<BF16>(ipw, wbase[jo] + k, w[jo]);
            #pragma unroll
            for (int rs = 0; rs < 12; ++rs) {
                const int r = rs / 3, s = rs % 3;
                const float* ap = &s_rows[r][s * 256 + k];
                float4 a0 = *(const float4*)ap;
                float4 a1 = *(const float4*)(ap + 4);
                float av[8] = {a0.x, a0.y, a0.z, a0.w, a1.x, a1.y, a1.z, a1.w};
                #pragma unroll
                for (int jo = 0; jo < 3; ++jo) {
                    #pragma unroll
                    for (int kk = 0; kk < 8; ++kk) acc[jo][rs] += av[kk] * w[jo][kk];
                }
            }
        }
        #pragma unroll
        for (int jo = 0; jo < 3; ++jo) {
            int j = tid + jo * 256;
            #pragma unroll
            for (int rs = 0; rs < 12; ++rs) s_qkv[rs / 3][rs % 3][j] = acc[jo][rs];
        }
    }
    __syncthreads();

    // ---- P2: attention per (r, head, s_q); ctx overwrites own q slice ----
    if (tid < 48) {
        int r = tid / 12;
        int h = (tid % 12) / 3;
        int sq = tid % 3;
        const float* qp = &s_qkv[r][sq][h * DD];
        float sc[3];
        #pragma unroll
        for (int sk = 0; sk < 3; ++sk) {
            const float* kp = &s_qkv[r][sk][256 + h * DD];
            float a = 0.f;
            #pragma unroll
            for (int d = 0; d < DD; d += 4) {
                float4 qv = *(const float4*)(qp + d);
                float4 kv = *(const float4*)(kp + d);
                a += qv.x*kv.x + qv.y*kv.y + qv.z*kv.z + qv.w*kv.w;
            }
            sc[sk] = a * 0.125f;
        }
        float m = fmaxf(sc[0], fmaxf(sc[1], sc[2]));
        float e0 = expf(sc[0] - m), e1 = expf(sc[1] - m), e2 = expf(sc[2] - m);
        float inv = 1.f / (e0 + e1 + e2);
        float a0 = e0 * inv, a1 = e1 * inv, a2 = e2 * inv;
        const float* v0 = &s_qkv[r][0][512 + h * DD];
        const float* v1 = &s_qkv[r][1][512 + h * DD];
        const float* v2 = &s_qkv[r][2][512 + h * DD];
        float* cp = &s_qkv[r][sq][h * DD];
        #pragma unroll
        for (int d = 0; d < DD; d += 4) {
            float4 x0 = *(const float4*)(v0 + d);
            float4 x1 = *(const float4*)(v1 + d);
            float4 x2 = *(const float4*)(v2 + d);
            float4 o;
            o.x = a0*x0.x + a1*x1.x + a2*x2.x;
            o.y = a0*x0.y + a1*x1.y + a2*x2.y;
            o.z = a0*x0.z + a1*x1.z + a2*x2.z;
            o.w = a0*x0.w + a1*x1.w + a2*x2.w;
            *(float4*)(cp + d) = o;
        }
    }
    __syncthreads();

    // ---- P3: att_out = ctx @ out_w.T + ob; +residual -> x in k-region ----
    {
        const int j = tid;
        float acc[12];
        float bias = ld1<BF16>(ob, j);
        #pragma unroll
        for (int rs = 0; rs < 12; ++rs) acc[rs] = bias;
        const size_t wbase = (size_t)j * E;
        for (int k = 0; k < E; k += 8) {
            float w[8]; ld8<BF16>(ow, wbase + k, w);
            #pragma unroll
            for (int rs = 0; rs < 12; ++rs) {
                const int r = rs / 3, s = rs % 3;
                const float* cp = &s_qkv[r][s][k];
                float4 c0 = *(const float4*)cp;
                float4 c1 = *(const float4*)(cp + 4);
                acc[rs] += c0.x*w[0] + c0.y*w[1] + c0.z*w[2] + c0.w*w[3]
                         + c1.x*w[4] + c1.y*w[5] + c1.z*w[6] + c1.w*w[7];
            }
        }
        #pragma unroll
        for (int rs = 0; rs < 12; ++rs) {
            const int r = rs / 3, s = rs % 3;
            s_qkv[r][s][256 + j] = acc[rs] + s_rows[r][s * 256 + j];
        }
    }
    __syncthreads();

    // ---- LN1 stats ----
    if (tid < 12) {
        int r = tid / 3, s = tid % 3;
        const float* xp = &s_qkv[r][s][256];
        float sum = 0.f, sq = 0.f;
        for (int c = 0; c < E; c += 4) {
            float4 v = *(const float4*)(xp + c);
            sum += v.x + v.y + v.z + v.w;
            sq  += v.x*v.x + v.y*v.y + v.z*v.z + v.w*v.w;
        }
        float mu = sum * (1.f / 256.f);
        float var = sq * (1.f / 256.f) - mu * mu;
        s_mu[tid] = mu;
        s_rstd[tid] = rsqrtf(var + 1e-5f);
    }
    __syncthreads();
    // ---- LN1 apply (in place) ----
    {
        float g = ld1<BF16>(ln1g, tid), b = ld1<BF16>(ln1b, tid);
        #pragma unroll
        for (int rs = 0; rs < 12; ++rs) {
            const int r = rs / 3, s = rs % 3;
            float x = s_qkv[r][s][256 + tid];
            s_qkv[r][s][256 + tid] = (x - s_mu[rs]) * s_rstd[rs] * g + b;
        }
    }
    __syncthreads();
    // ---- P4: gate ----
    if (tid < 12) {
        int r = tid / 3, g = tid % 3;
        float acc = ld1<BF16>(gb, g);
        const size_t gwb = (size_t)g * 768;
        const float* rp = s_rows[r];
        for (int k = 0; k < 768; k += 4) {
            float w[4]; ld4<BF16>(gw, gwb + k, w);
            float4 x = *(const float4*)(rp + k);
            acc += x.x*w[0] + x.y*w[1] + x.z*w[2] + x.w*w[3];
        }
        s_wgt[r][g] = acc;
    }
    __syncthreads();
    if (tid < RPB) {
        float l0 = s_wgt[tid][0], l1 = s_wgt[tid][1], l2 = s_wgt[tid][2];
        float m = fmaxf(l0, fmaxf(l1, l2));
        float e0 = expf(l0 - m), e1 = expf(l1 - m), e2 = expf(l2 - m);
        float inv = 1.f / (e0 + e1 + e2);
        s_wgt[tid][0] = e0 * inv; s_wgt[tid][1] = e1 * inv; s_wgt[tid][2] = e2 * inv;
    }
    __syncthreads();

    // ---- P5: fused = sum_s wgt[s]*x[s] -> global + v-region s=0 ----
    #pragma unroll
    for (int r = 0; r < RPB; ++r) {
        float v = s_qkv[r][0][256 + tid] * s_wgt[r][0]
                + s_qkv[r][1][256 + tid] * s_wgt[r][1]
                + s_qkv[r][2][256 + tid] * s_wgt[r][2];
        s_qkv[r][0][512 + tid] = v;
        if (row0 + r < nrows)
            st1<BF16>(d_out, fused_base + (size_t)(row0 + r) * E + tid, v);
    }
    __syncthreads();

    // ---- LN2 stats + apply ----
    if (tid < RPB) {
        const float* fp = &s_qkv[tid][0][512];
        float sum = 0.f, sq = 0.f;
        for (int c = 0; c < E; c += 4) {
            float4 v = *(const float4*)(fp + c);
            sum += v.x + v.y + v.z + v.w;
            sq  += v.x*v.x + v.y*v.y + v.z*v.z + v.w*v.w;
        }
        float mu = sum * (1.f / 256.f);
        float var = sq * (1.f / 256.f) - mu * mu;
        s_mu2[tid] = mu;
        s_rstd2[tid] = rsqrtf(var + 1e-5f);
    }
    __syncthreads();
    {
        float g = ld1<BF16>(ln2g, tid), b = ld1<BF16>(ln2b, tid);
        #pragma unroll
        for (int r = 0; r < RPB; ++r) {
            float x = s_qkv[r][0][512 + tid];
            s_qkv[r][0][512 + tid] = (x - s_mu2[r]) * s_rstd2[r] * g + b;
        }
    }
    __syncthreads();

    // ---- P6: h1 = gelu(h0 @ w1.T + b1) ----
    {
        const int j = tid;
        float acc[RPB];
        float bias = ld1<BF16>(bb1, j);
        #pragma unroll
        for (int r = 0; r < RPB; ++r) acc[r] = bias;
        const size_t wbase = (size_t)j * E;
        for (int k = 0; k < E; k += 8) {
            float w[8]; ld8<BF16>(w1, wbase + k, w);
            #pragma unroll
            for (int r = 0; r < RPB; ++r) {
                const float* hp = &s_qkv[r][0][512 + k];
                float4 h0 = *(const float4*)hp;
                float4 h1v = *(const float4*)(hp + 4);
                acc[r] += h0.x*w[0] + h0.y*w[1] + h0.z*w[2] + h0.w*w[3]
                        + h1v.x*w[4] + h1v.y*w[5] + h1v.z*w[6] + h1v.w*w[7];
            }
        }
        #pragma unroll
        for (int r = 0; r < RPB; ++r) {
            float x = acc[r];
            s_qkv[r][1][512 + j] = 0.5f * x * (1.f + erff(x * 0.70710678118654752f));
        }
    }
    __syncthreads();

    // ---- P7: h2 = gelu(h1 @ w2.T + b2) ----
    if (tid < 128) {
        const int j = tid;
        float acc[RPB];
        float bias = ld1<BF16>(bb2, j);
        #pragma unroll
        for (int r = 0; r < RPB; ++r) acc[r] = bias;
        const size_t wbase = (size_t)j * E;
        for (int k = 0; k < E; k += 8) {
            float w[8]; ld8<BF16>(w2, wbase + k, w);
            #pragma unroll
            for (int r = 0; r < RPB; ++r) {
                const float* hp = &s_qkv[r][1][512 + k];
                float4 h0 = *(const float4*)hp;
                float4 h1v = *(const float4*)(hp + 4);
                acc[r] += h0.x*w[0] + h0.y*w[1] + h0.z*w[2] + h0.w*w[3]
                        + h1v.x*w[4] + h1v.y*w[5] + h1v.z*w[6] + h1v.w*w[7];
            }
        }
        #pragma unroll
        for (int r = 0; r < RPB; ++r) {
            float x = acc[r];
            s_qkv[r][2][512 + j] = 0.5f * x * (1.f + erff(x * 0.70710678118654752f));
        }
    }
    __syncthreads();

    // ---- P8: logits = h2 @ w3.T + b3 ----
    if (tid < RPB * NC) {
        int r = tid / NC, n = tid - r * NC;
        float acc = ld1<BF16>(bb3, n);
        const size_t wbase = (size_t)n * 128;
        const float* hp = &s_qkv[r][2][512];
        #pragma unroll
        for (int k = 0; k < 128; k += 4) {
            float w[4]; ld4<BF16>(w3, wbase + k, w);
            float4 h = *(const float4*)(hp + k);
            acc += h.x*w[0] + h.y*w[1] + h.z*w[2] + h.w*w[3];
        }
        if (row0 + r < nrows)
            st1<BF16>(d_out, (size_t)(row0 + r) * NC + n, acc);
    }
}

extern "C" void kernel_launch(void* const* d_in, const int* in_sizes, int n_in,
                              void* d_out, int out_size, void* d_ws, size_t ws_size,
                              hipStream_t stream) {
    (void)n_in; (void)ws_size; (void)out_size;
    const int nrows = in_sizes[0] / E;           // B
    int* flag = (int*)d_ws;
    dtype_detect_kernel<<<1, 64, 0, stream>>>((const u32*)d_in[7], flag);
    const int nblocks = (nrows + RPB - 1) / RPB;
    dhc_fused_kernel<true><<<nblocks, NT, 0, stream>>>(
        d_in[0], d_in[1], d_in[2], d_in[3], d_in[4], d_in[5], d_in[6],
        d_in[7], d_in[8], d_in[9], d_in[10], d_in[11], d_in[12],
        d_in[13], d_in[14], d_in[15], d_in[16], d_in[17], d_in[18],
        d_out, flag, nrows);
    dhc_fused_kernel<false><<<nblocks, NT, 0, stream>>>(
        d_in[0], d_in[1], d_in[2], d_in[3], d_in[4], d_in[5], d_in[6],
        d_in[7], d_in[8], d_in[9], d_in[10], d_in[11], d_in[12],
        d_in[13], d_in[14], d_in[15], d_in[16], d_in[17], d_in[18],
        d_out, flag, nrows);
}

// Round 3
// 707.118 us; speedup vs baseline: 4.3817x; 4.3817x over previous
//
#include <hip/hip_runtime.h>
#include <math.h>

// DeepHeadClassifier — round 3: MFMA (bf16) fully-fused kernel. fp32 I/O proven
// in round 2 (fp32 variant passed; WRITE_SIZE == fp32 output size).
// Block = 16 rows = 48 tokens (token t = s*16+r, s-major so m-tiles align with
// sources). Weights pre-converted fp32->bf16 into d_ws once per launch.
// GEMMs: qk (2 head-pair passes, N=256), v (N=256), out_proj (N=256),
// w1 (N=256), w2 (N=128) via v_mfma_f32_16x16x32_bf16.
// A from LDS (ds_read_b128, stride 264 -> 2-way bank alias = free),
// B from global ws (L2-hot, [N][K] bf16 rows = native B-frag layout).
// LDS ~54 KB -> 2 blocks/CU.

#define E   256
#define NC  7
#define BM  16      // rows per block
#define TOK 48      // tokens per block
#define NT  256
#define BS  264     // LDS row stride (elements)

typedef unsigned short u16;
typedef unsigned int   u32;
typedef __attribute__((ext_vector_type(8))) short  short8;
typedef __attribute__((ext_vector_type(4))) float  f32x4;

// ws layout (bf16 elements)
#define O_IPW 0
#define O_OW  196608
#define O_GW  262144
#define O_W1  264448
#define O_W2  329984
#define CVT_TOTAL 362752

__device__ __forceinline__ float bf2f(u32 u) { return __uint_as_float(u << 16); }
__device__ __forceinline__ u16 f2bf(float f) {
    u32 u = __float_as_uint(f);
    return (u16)((u + 0x7fffu + ((u >> 16) & 1u)) >> 16);
}

__global__ void cvt_weights(const float* __restrict__ ipw, const float* __restrict__ ow,
                            const float* __restrict__ gw,  const float* __restrict__ w1,
                            const float* __restrict__ w2,  u16* __restrict__ ws) {
    int i4 = (blockIdx.x * 256 + threadIdx.x) * 4;
    if (i4 >= CVT_TOTAL) return;
    const float* src; int off;
    if      (i4 < O_OW)  { src = ipw; off = i4; }
    else if (i4 < O_GW)  { src = ow;  off = i4 - O_OW; }
    else if (i4 < O_W1)  { src = gw;  off = i4 - O_GW; }
    else if (i4 < O_W2)  { src = w1;  off = i4 - O_W1; }
    else                 { src = w2;  off = i4 - O_W2; }
    float4 v = *(const float4*)(src + off);
    ushort4 o;
    o.x = f2bf(v.x); o.y = f2bf(v.y); o.z = f2bf(v.z); o.w = f2bf(v.w);
    *(ushort4*)(ws + i4) = o;
}

// GEMM over K=256: A from LDS (token-major, stride BS), B rows from ws bf16.
// Wave-tile: MT m-tiles x NTW n-tiles of 16x16, K-steps of 32.
template<int MT, int NTW>
__device__ __forceinline__ void mfma_gemm(const u16* aLds, int aRow0,
                                          const u16* __restrict__ bW, int rowBase,
                                          int lane, f32x4 acc[MT][NTW]) {
    const int l16 = lane & 15, quad = lane >> 4;
    #pragma unroll
    for (int m = 0; m < MT; ++m)
        #pragma unroll
        for (int j = 0; j < NTW; ++j) acc[m][j] = (f32x4){0.f, 0.f, 0.f, 0.f};
    #pragma unroll 2
    for (int ks = 0; ks < 8; ++ks) {
        short8 a[MT];
        #pragma unroll
        for (int m = 0; m < MT; ++m)
            a[m] = *(const short8*)(aLds + (size_t)(aRow0 + m * 16 + l16) * BS + ks * 32 + quad * 8);
        #pragma unroll
        for (int j = 0; j < NTW; ++j) {
            short8 b = *(const short8*)(bW + (size_t)(rowBase + j * 16 + l16) * 256 + ks * 32 + quad * 8);
            #pragma unroll
            for (int m = 0; m < MT; ++m)
                acc[m][j] = __builtin_amdgcn_mfma_f32_16x16x32_bf16(a[m], b, acc[m][j], 0, 0, 0);
        }
    }
}

__global__ __launch_bounds__(NT, 2)
void dhc_mfma_kernel(
    const float* __restrict__ f0, const float* __restrict__ f1, const float* __restrict__ f2,
    const float* __restrict__ ipb, const float* __restrict__ ob,
    const float* __restrict__ ln1g, const float* __restrict__ ln1b,
    const float* __restrict__ gb,
    const float* __restrict__ ln2g, const float* __restrict__ ln2b,
    const float* __restrict__ b1, const float* __restrict__ b2,
    const float* __restrict__ w3, const float* __restrict__ b3,
    const u16* __restrict__ ws, float* __restrict__ d_out, int nrows)
{
    __shared__ __align__(16) u16 s_x[TOK * BS];    // stacked bf16, persists
    __shared__ __align__(16) u16 s_buf[TOK * BS];  // qk -> v/ctx -> x_res/x_ln -> fused/h0/h1/h2
    __shared__ float s_attn[BM][4][9];
    __shared__ float s_gp[BM][9];
    __shared__ float s_wgt[BM][3];
    __shared__ float s_mu[TOK], s_rstd[TOK];
    __shared__ float s_mu2[BM], s_rstd2[BM];

    const int tid  = threadIdx.x;
    const int wid  = tid >> 6, lane = tid & 63;
    const int l16  = lane & 15, quad = lane >> 4;
    const long long row0 = (long long)blockIdx.x * BM;
    const size_t fused_base = (size_t)nrows * NC;

    const u16* ipw_b = ws + O_IPW;
    const u16* ow_b  = ws + O_OW;
    const u16* gw_b  = ws + O_GW;
    const u16* w1_b  = ws + O_W1;
    const u16* w2_b  = ws + O_W2;

    // ---- P0: stacked fp32 -> bf16 LDS (token t = s*16+r) ----
    #pragma unroll
    for (int it = 0; it < 12; ++it) {
        int id = it * NT + tid;            // vec4 chunk over 48*256/4 = 3072
        int t  = id >> 6;                  // token
        int c4 = (id & 63) * 4;
        int s  = t >> 4, r = t & 15;
        float4 v = {0.f, 0.f, 0.f, 0.f};
        if (row0 + r < nrows) {
            const float* src = (s == 0 ? f0 : (s == 1 ? f1 : f2));
            v = *(const float4*)(src + (size_t)(row0 + r) * E + c4);
        }
        ushort4 o;
        o.x = f2bf(v.x); o.y = f2bf(v.y); o.z = f2bf(v.z); o.w = f2bf(v.w);
        *(ushort4*)(s_x + t * BS + c4) = o;
    }
    __syncthreads();

    // ---- qk passes: p=0 -> heads 0,1 ; p=1 -> heads 2,3 ----
    for (int p = 0; p < 2; ++p) {
        // G1: buf cols [0,128) = q feats 128p.. ; [128,256) = k feats 128p..
        const int rowBase = (wid < 2) ? (128 * p + 64 * wid) : (256 + 128 * p + 64 * (wid - 2));
        f32x4 acc[3][4];
        mfma_gemm<3, 4>(s_x, 0, ipw_b, rowBase, lane, acc);
        #pragma unroll
        for (int j = 0; j < 4; ++j) {
            int n = wid * 64 + j * 16 + l16;
            float bias = ipb[rowBase + j * 16 + l16];
            #pragma unroll
            for (int m = 0; m < 3; ++m)
                #pragma unroll
                for (int rr = 0; rr < 4; ++rr) {
                    int tok = m * 16 + quad * 4 + rr;
                    s_buf[tok * BS + n] = f2bf(acc[m][j][rr] + bias);
                }
        }
        __syncthreads();
        // ---- P2: scores + softmax for heads 2p, 2p+1 ----
        if (tid < 96) {
            int r = tid / 6, rem = tid % 6;
            int hh = rem / 3, i = rem % 3;
            int h = 2 * p + hh;
            float d0 = 0.f, d1 = 0.f, d2 = 0.f;
            const u16* qrow = s_buf + (i * 16 + r) * BS + hh * 64;
            const u16* k0 = s_buf + (0 * 16 + r) * BS + 128 + hh * 64;
            const u16* k1 = s_buf + (1 * 16 + r) * BS + 128 + hh * 64;
            const u16* k2 = s_buf + (2 * 16 + r) * BS + 128 + hh * 64;
            for (int d8 = 0; d8 < 8; ++d8) {
                short8 qv = *(const short8*)(qrow + d8 * 8);
                short8 a0 = *(const short8*)(k0 + d8 * 8);
                short8 a1 = *(const short8*)(k1 + d8 * 8);
                short8 a2 = *(const short8*)(k2 + d8 * 8);
                #pragma unroll
                for (int e = 0; e < 8; ++e) {
                    float q = bf2f((u32)(u16)qv[e]);
                    d0 += q * bf2f((u32)(u16)a0[e]);
                    d1 += q * bf2f((u32)(u16)a1[e]);
                    d2 += q * bf2f((u32)(u16)a2[e]);
                }
            }
            d0 *= 0.125f; d1 *= 0.125f; d2 *= 0.125f;
            float mx = fmaxf(d0, fmaxf(d1, d2));
            float e0 = expf(d0 - mx), e1 = expf(d1 - mx), e2 = expf(d2 - mx);
            float inv = 1.f / (e0 + e1 + e2);
            s_attn[r][h][i * 3 + 0] = e0 * inv;
            s_attn[r][h][i * 3 + 1] = e1 * inv;
            s_attn[r][h][i * 3 + 2] = e2 * inv;
        }
        __syncthreads();
    }

    // ---- G2: v = x @ ipw[512:768]^T + b -> buf[:, 0:256) ----
    {
        const int rowBase = 512 + 64 * wid;
        f32x4 acc[3][4];
        mfma_gemm<3, 4>(s_x, 0, ipw_b, rowBase, lane, acc);
        #pragma unroll
        for (int j = 0; j < 4; ++j) {
            int n = wid * 64 + j * 16 + l16;
            float bias = ipb[rowBase + j * 16 + l16];
            #pragma unroll
            for (int m = 0; m < 3; ++m)
                #pragma unroll
                for (int rr = 0; rr < 4; ++rr) {
                    int tok = m * 16 + quad * 4 + rr;
                    s_buf[tok * BS + n] = f2bf(acc[m][j][rr] + bias);
                }
        }
    }
    __syncthreads();

    // ---- P4: ctx = attn (x) v, in place (thread owns (r, 16-col slice)) ----
    {
        int r = tid >> 4;
        int cb = (tid & 15) * 16;
        int h = cb >> 6;
        float a[9];
        #pragma unroll
        for (int q2 = 0; q2 < 9; ++q2) a[q2] = s_attn[r][h][q2];
        #pragma unroll
        for (int cc = 0; cc < 16; ++cc) {
            int c = cb + cc;
            float v0 = bf2f((u32)s_buf[(0 * 16 + r) * BS + c]);
            float v1 = bf2f((u32)s_buf[(1 * 16 + r) * BS + c]);
            float v2 = bf2f((u32)s_buf[(2 * 16 + r) * BS + c]);
            float c0 = a[0] * v0 + a[1] * v1 + a[2] * v2;
            float c1 = a[3] * v0 + a[4] * v1 + a[5] * v2;
            float c2 = a[6] * v0 + a[7] * v1 + a[8] * v2;
            s_buf[(0 * 16 + r) * BS + c] = f2bf(c0);
            s_buf[(1 * 16 + r) * BS + c] = f2bf(c1);
            s_buf[(2 * 16 + r) * BS + c] = f2bf(c2);
        }
    }
    __syncthreads();

    // ---- G3: att_out = ctx @ ow^T + ob; + residual -> x_res bf16 in buf ----
    {
        const int rowBase = 64 * wid;
        f32x4 acc[3][4];
        mfma_gemm<3, 4>(s_buf, 0, ow_b, rowBase, lane, acc);
        #pragma unroll
        for (int j = 0; j < 4; ++j) {
            int n = rowBase + j * 16 + l16;
            float bias = ob[n];
            #pragma unroll
            for (int m = 0; m < 3; ++m)
                #pragma unroll
                for (int rr = 0; rr < 4; ++rr) {
                    int tok = m * 16 + quad * 4 + rr;
                    acc[m][j][rr] += bias + bf2f((u32)s_x[tok * BS + n]);
                }
        }
        __syncthreads();   // all waves done reading ctx
        #pragma unroll
        for (int j = 0; j < 4; ++j) {
            int n = rowBase + j * 16 + l16;
            #pragma unroll
            for (int m = 0; m < 3; ++m)
                #pragma unroll
                for (int rr = 0; rr < 4; ++rr) {
                    int tok = m * 16 + quad * 4 + rr;
                    s_buf[tok * BS + n] = f2bf(acc[m][j][rr]);
                }
        }
    }
    __syncthreads();

    // ---- LN1 stats (48 tokens) ----
    if (tid < TOK) {
        const u16* xp = s_buf + tid * BS;
        float sum = 0.f, sq = 0.f;
        for (int c8 = 0; c8 < 32; ++c8) {
            short8 v = *(const short8*)(xp + c8 * 8);
            #pragma unroll
            for (int e = 0; e < 8; ++e) {
                float x = bf2f((u32)(u16)v[e]);
                sum += x; sq += x * x;
            }
        }
        float mu = sum * (1.f / 256.f);
        float var = sq * (1.f / 256.f) - mu * mu;
        s_mu[tid] = mu;
        s_rstd[tid] = rsqrtf(var + 1e-5f);
    }
    __syncthreads();
    // ---- LN1 apply in place (thread = column) ----
    {
        float g = ln1g[tid], b = ln1b[tid];
        #pragma unroll 4
        for (int t = 0; t < TOK; ++t) {
            float x = bf2f((u32)s_buf[t * BS + tid]);
            s_buf[t * BS + tid] = f2bf((x - s_mu[t]) * s_rstd[t] * g + b);
        }
    }
    __syncthreads();

    // ---- Gate: logits_g = concat(x) . gw_g  (partials over 3 segments) ----
    if (tid < 144) {
        int r = tid / 9, rem = tid % 9;
        int g = rem / 3, s = rem % 3;
        const u16* xp = s_x + (s * 16 + r) * BS;
        const u16* wp = gw_b + g * 768 + s * 256;
        float acc = 0.f;
        for (int c8 = 0; c8 < 32; ++c8) {
            short8 xv = *(const short8*)(xp + c8 * 8);
            short8 wv = *(const short8*)(wp + c8 * 8);
            #pragma unroll
            for (int e = 0; e < 8; ++e)
                acc += bf2f((u32)(u16)xv[e]) * bf2f((u32)(u16)wv[e]);
        }
        s_gp[r][g * 3 + s] = acc;
    }
    __syncthreads();
    if (tid < 48) {
        int r = tid / 3, g = tid % 3;
        s_wgt[r][g] = gb[g] + s_gp[r][g * 3 + 0] + s_gp[r][g * 3 + 1] + s_gp[r][g * 3 + 2];
    }
    __syncthreads();
    if (tid < BM) {
        float l0 = s_wgt[tid][0], l1 = s_wgt[tid][1], l2 = s_wgt[tid][2];
        float mx = fmaxf(l0, fmaxf(l1, l2));
        float e0 = expf(l0 - mx), e1 = expf(l1 - mx), e2 = expf(l2 - mx);
        float inv = 1.f / (e0 + e1 + e2);
        s_wgt[tid][0] = e0 * inv; s_wgt[tid][1] = e1 * inv; s_wgt[tid][2] = e2 * inv;
    }
    __syncthreads();

    // ---- fused = sum_s wgt*x_ln -> global fp32 + buf rows[0:16) bf16 ----
    {
        int c = tid;
        float* outF = d_out + fused_base;
        #pragma unroll 4
        for (int r = 0; r < BM; ++r) {
            float f = s_wgt[r][0] * bf2f((u32)s_buf[(0 * 16 + r) * BS + c])
                    + s_wgt[r][1] * bf2f((u32)s_buf[(1 * 16 + r) * BS + c])
                    + s_wgt[r][2] * bf2f((u32)s_buf[(2 * 16 + r) * BS + c]);
            if (row0 + r < nrows) outF[(size_t)(row0 + r) * E + c] = f;
            s_buf[r * BS + c] = f2bf(f);
        }
    }
    __syncthreads();

    // ---- LN2 stats + apply -> h0 in buf rows[0:16) ----
    if (tid < BM) {
        const u16* fp = s_buf + tid * BS;
        float sum = 0.f, sq = 0.f;
        for (int c8 = 0; c8 < 32; ++c8) {
            short8 v = *(const short8*)(fp + c8 * 8);
            #pragma unroll
            for (int e = 0; e < 8; ++e) {
                float x = bf2f((u32)(u16)v[e]);
                sum += x; sq += x * x;
            }
        }
        float mu = sum * (1.f / 256.f);
        float var = sq * (1.f / 256.f) - mu * mu;
        s_mu2[tid] = mu;
        s_rstd2[tid] = rsqrtf(var + 1e-5f);
    }
    __syncthreads();
    {
        float g = ln2g[tid], b = ln2b[tid];
        #pragma unroll
        for (int r = 0; r < BM; ++r) {
            float x = bf2f((u32)s_buf[r * BS + tid]);
            s_buf[r * BS + tid] = f2bf((x - s_mu2[r]) * s_rstd2[r] * g + b);
        }
    }
    __syncthreads();

    // ---- G4: h1 = gelu(h0 @ w1^T + b1) -> buf rows [16,32) ----
    {
        const int rowBase = 64 * wid;
        f32x4 acc[1][4];
        mfma_gemm<1, 4>(s_buf, 0, w1_b, rowBase, lane, acc);
        __syncthreads();   // all reads of h0 done before h1 writes (disjoint rows anyway)
        #pragma unroll
        for (int j = 0; j < 4; ++j) {
            int n = rowBase + j * 16 + l16;
            float bias = b1[n];
            #pragma unroll
            for (int rr = 0; rr < 4; ++rr) {
                int r = quad * 4 + rr;
                float x = acc[0][j][rr] + bias;
                float hgelu = 0.5f * x * (1.f + erff(x * 0.70710678118654752f));
                s_buf[(16 + r) * BS + n] = f2bf(hgelu);
            }
        }
    }
    __syncthreads();

    // ---- G5: h2 = gelu(h1 @ w2^T + b2) -> buf rows [32,48), cols [0,128) ----
    {
        const int rowBase = 32 * wid;
        f32x4 acc[1][2];
        mfma_gemm<1, 2>(s_buf, 16, w2_b, rowBase, lane, acc);
        __syncthreads();
        #pragma unroll
        for (int j = 0; j < 2; ++j) {
            int n = rowBase + j * 16 + l16;
            float bias = b2[n];
            #pragma unroll
            for (int rr = 0; rr < 4; ++rr) {
                int r = quad * 4 + rr;
                float x = acc[0][j][rr] + bias;
                float hgelu = 0.5f * x * (1.f + erff(x * 0.70710678118654752f));
                s_buf[(32 + r) * BS + n] = f2bf(hgelu);
            }
        }
    }
    __syncthreads();

    // ---- logits = h2 @ w3^T + b3 -> global fp32 ----
    if (tid < BM * NC) {
        int r = tid / NC, n = tid % NC;
        float acc = b3[n];
        const float* wr = w3 + n * 128;
        const u16* hp = s_buf + (32 + r) * BS;
        for (int k4 = 0; k4 < 32; ++k4) {
            float4 w = *(const float4*)(wr + k4 * 4);
            acc += bf2f((u32)hp[k4 * 4 + 0]) * w.x
                 + bf2f((u32)hp[k4 * 4 + 1]) * w.y
                 + bf2f((u32)hp[k4 * 4 + 2]) * w.z
                 + bf2f((u32)hp[k4 * 4 + 3]) * w.w;
        }
        if (row0 + r < nrows) d_out[(size_t)(row0 + r) * NC + n] = acc;
    }
}

extern "C" void kernel_launch(void* const* d_in, const int* in_sizes, int n_in,
                              void* d_out, int out_size, void* d_ws, size_t ws_size,
                              hipStream_t stream) {
    (void)n_in; (void)ws_size; (void)out_size;
    const int nrows = in_sizes[0] / E;
    u16* ws = (u16*)d_ws;
    cvt_weights<<<(CVT_TOTAL / 4 + 255) / 256, 256, 0, stream>>>(
        (const float*)d_in[3], (const float*)d_in[5], (const float*)d_in[9],
        (const float*)d_in[13], (const float*)d_in[15], ws);
    const int nblocks = (nrows + BM - 1) / BM;
    dhc_mfma_kernel<<<nblocks, NT, 0, stream>>>(
        (const float*)d_in[0], (const float*)d_in[1], (const float*)d_in[2],
        (const float*)d_in[4], (const float*)d_in[6],
        (const float*)d_in[7], (const float*)d_in[8],
        (const float*)d_in[10],
        (const float*)d_in[11], (const float*)d_in[12],
        (const float*)d_in[14], (const float*)d_in[16],
        (const float*)d_in[17], (const float*)d_in[18],
        ws, (float*)d_out, nrows);
}